// Round 1
// baseline (207.778 us; speedup 1.0000x reference)
//
#include <hip/hip_runtime.h>

// GaussianSplatter: out[(bl,c),(y,x)] = clip( sum_p A[(bl,c),p] * KY[p,y]*KX[p,x] )
// M=4096 (=64 patches * 64 ch), N=2304 (=48*48 pixels), K=2304 (=48*48 points)

#define NPTS 2304
#define KD   2304
#define MD   4096
#define HH   192
#define BMv  128
#define BNv  128
#define BKv  32
#define LDK  40   // BKv + 8 halves pad -> 80B row stride, 2-way (free) bank aliasing

typedef _Float16 f16;
typedef _Float16 f16x8 __attribute__((ext_vector_type(8)));
typedef float f32x4 __attribute__((ext_vector_type(4)));

// one bilinear tap of the padded 1-D gaussian: taps t in [13,33] hold exp(-(0.5t-11.5)^2 * inv2s)
__device__ __forceinline__ float gtap(float t, float inv2s) {
    float ax = 0.5f * t - 11.5f;
    float g = expf(-ax * ax * inv2s);
    return (t >= 12.5f && t <= 33.5f) ? g : 0.0f;
}

// KY_T[y][p], KX_T[x][p]  (transposed for coalesced reads in build_kt)
__global__ void build_kykx(const float* __restrict__ sx, const float* __restrict__ sy,
                           const float* __restrict__ op,
                           float* __restrict__ KY_T, float* __restrict__ KX_T) {
    int flat = blockIdx.x * 256 + threadIdx.x;      // 48*2304 = 110592
    if (flat >= 48 * NPTS) return;
    int pos = flat / NPTS;            // output pixel coord (y for KY, x for KX), 0..47
    int p   = flat - pos * NPTS;      // point index
    int i = p / 48;
    int j = p - i * 48;
    float sxv = sx[p], syv = sy[p], opv = op[p];
    float invx = 0.5f / (sxv * sxv);  // h-axis uses sigma_x (reference: xx2/sx2 on axis 1)
    float invy = 0.5f / (syv * syv);  // w-axis uses sigma_y

    // KY: sample padded gaussian at py = pos + ty*23.5, ty = 1 - 2i/48
    float py = (float)pos + 23.5f - (47.0f / 48.0f) * (float)i;
    float y0 = floorf(py), fy = py - y0;
    float ky = gtap(y0, invx) * (1.0f - fy) + gtap(y0 + 1.0f, invx) * fy;
    KY_T[flat] = opv * ky;            // fold opacity here

    // KX: px = pos + tx*23.5, tx = 1 - 2j/48
    float px = (float)pos + 23.5f - (47.0f / 48.0f) * (float)j;
    float x0 = floorf(px), fx = px - x0;
    float kx = gtap(x0, invy) * (1.0f - fx) + gtap(x0 + 1.0f, invy) * fx;
    KX_T[flat] = kx;
}

// Kt_T[hw][p] = (f16)(KY[p,y]*KX[p,x])  -- stored transposed so GEMM stages it contiguous-in-K
__global__ void build_kt(const float* __restrict__ KY_T, const float* __restrict__ KX_T,
                         f16* __restrict__ Kt) {
    int hw = blockIdx.x;              // 0..2303
    int y = hw / 48, x = hw - y * 48;
    const float* kyr = KY_T + (size_t)y * NPTS;
    const float* kxr = KX_T + (size_t)x * NPTS;
    f16* dst = Kt + (size_t)hw * NPTS;
    for (int p = threadIdx.x; p < NPTS; p += 256)
        dst[p] = (f16)(kyr[p] * kxr[p]);
}

// A[m][p] fp16, m = bl*64 + c, p = i*48 + j ; bl = b*16 + pr*4 + pc
__global__ void pack_A(const float* __restrict__ inp, f16* __restrict__ A) {
    int m = blockIdx.x;               // 0..4095
    int bl = m >> 6, c = m & 63;
    int b = bl >> 4, pr = (bl >> 2) & 3, pc = bl & 3;
    const float* src = inp + (((size_t)(b * 64 + c)) * HH + pr * 48) * HH + pc * 48;
    f16* dst = A + (size_t)m * KD;
    for (int p = threadIdx.x; p < NPTS; p += 256) {
        int i = p / 48, j = p - i * 48;
        dst[p] = (f16)src[i * HH + j];
    }
}

// C[m][n] = sum_k A[m][k] * Bt[n][k];  epilogue: clip to [0,1], scatter-fold into out[B,C,H,W]
__global__ __launch_bounds__(256) void gemm_splat(const f16* __restrict__ A,
                                                  const f16* __restrict__ Bt,
                                                  float* __restrict__ out) {
    __shared__ __attribute__((aligned(16))) f16 As[BMv * LDK];
    __shared__ __attribute__((aligned(16))) f16 Bs[BNv * LDK];

    int tid  = threadIdx.x;
    int lane = tid & 63;
    int w    = tid >> 6;          // wave 0..3
    int wr   = w >> 1, wc = w & 1;
    int bx   = blockIdx.x;
    int m0   = (bx / 18) * BMv;   // N/BN = 2304/128 = 18
    int n0   = (bx % 18) * BNv;

    const int lrow = lane & 15;
    const int lk8  = (lane >> 4) * 8;

    f32x4 acc[4][4] = {};

    for (int k0 = 0; k0 < KD; k0 += BKv) {
        // stage A-tile and Bt-tile (both row-major in K -> contiguous 16B chunks)
        #pragma unroll
        for (int it = 0; it < 2; ++it) {
            int idx = tid + it * 256;           // 0..511 chunks
            int row = idx >> 2;                 // 4 chunks of 8 halves per row
            int ko  = (idx & 3) * 8;
            *(f16x8*)&As[row * LDK + ko] = *(const f16x8*)&A [(size_t)(m0 + row) * KD + k0 + ko];
            *(f16x8*)&Bs[row * LDK + ko] = *(const f16x8*)&Bt[(size_t)(n0 + row) * KD + k0 + ko];
        }
        __syncthreads();

        f16x8 af[4], bf[4];
        #pragma unroll
        for (int mi = 0; mi < 4; ++mi)
            af[mi] = *(const f16x8*)&As[(wr * 64 + mi * 16 + lrow) * LDK + lk8];
        #pragma unroll
        for (int ni = 0; ni < 4; ++ni)
            bf[ni] = *(const f16x8*)&Bs[(wc * 64 + ni * 16 + lrow) * LDK + lk8];

        #pragma unroll
        for (int mi = 0; mi < 4; ++mi)
            #pragma unroll
            for (int ni = 0; ni < 4; ++ni)
                acc[mi][ni] = __builtin_amdgcn_mfma_f32_16x16x32_f16(af[mi], bf[ni], acc[mi][ni], 0, 0, 0);
        __syncthreads();
    }

    // epilogue: D row = (lane>>4)*4 + r, col = lane&15 (m89-verified C/D layout)
    #pragma unroll
    for (int mi = 0; mi < 4; ++mi) {
        #pragma unroll
        for (int r = 0; r < 4; ++r) {
            int m  = m0 + wr * 64 + mi * 16 + (lane >> 4) * 4 + r;
            int bl = m >> 6, c = m & 63;
            int b  = bl >> 4, pr = (bl >> 2) & 3, pc = bl & 3;
            float* orow = out + ((size_t)(b * 64 + c) * HH + pr * 48) * HH + pc * 48;
            #pragma unroll
            for (int ni = 0; ni < 4; ++ni) {
                int n = n0 + wc * 64 + ni * 16 + (lane & 15);
                int y = n / 48, x = n - y * 48;
                float v = acc[mi][ni][r];
                v = fminf(fmaxf(v, 0.0f), 1.0f);
                orow[y * HH + x] = v;
            }
        }
    }
}

extern "C" void kernel_launch(void* const* d_in, const int* in_sizes, int n_in,
                              void* d_out, int out_size, void* d_ws, size_t ws_size,
                              hipStream_t stream) {
    const float* inp = (const float*)d_in[0];
    const float* sx  = (const float*)d_in[1];
    const float* sy  = (const float*)d_in[2];
    const float* op  = (const float*)d_in[3];
    float* out = (float*)d_out;

    char* ws = (char*)d_ws;
    float* KY_T = (float*)ws;                               //   442368 B
    float* KX_T = (float*)(ws + 442368);                    //   442368 B
    f16*   Kt   = (f16*)(ws + 884736);                      // 10616832 B  [2304][2304]
    f16*   Ap   = (f16*)(ws + 884736 + 10616832);           // 18874368 B  [4096][2304]

    build_kykx<<<dim3(432), dim3(256), 0, stream>>>(sx, sy, op, KY_T, KX_T);
    build_kt  <<<dim3(2304), dim3(256), 0, stream>>>(KY_T, KX_T, Kt);
    pack_A    <<<dim3(4096), dim3(256), 0, stream>>>(inp, Ap);
    gemm_splat<<<dim3(576), dim3(256), 0, stream>>>(Ap, Kt, out);
}

// Round 2
// 146.377 us; speedup vs baseline: 1.4195x; 1.4195x over previous
//
#include <hip/hip_runtime.h>

// GaussianSplatter: out[(bl,c),(y,x)] = clip( sum_p A[(bl,c),p] * KY[p,y]*KX[p,x] )
// M=4096 (=64 patches * 64 ch), N=2304 (=48*48 pixels), K=2304 (=48*48 points)
// K-band: KY[p,y]!=0  <=>  y-10.5 < (47/48)*i < y+11.5  (i = p/48) -> ~54% of K per n-tile

#define NPTS 2304
#define KD   2304
#define HH   192

typedef _Float16 f16;
typedef _Float16 f16x8 __attribute__((ext_vector_type(8)));
typedef float f32x4 __attribute__((ext_vector_type(4)));

__device__ __forceinline__ void gload16(const f16* g, f16* l) {
    // 16B per lane; LDS dest is wave-uniform base + lane*16 (m97 pattern)
    __builtin_amdgcn_global_load_lds((const __attribute__((address_space(1))) void*)g,
                                     (__attribute__((address_space(3))) void*)l,
                                     16, 0, 0);
}

// one bilinear tap of the padded 1-D gaussian: taps t in [13,33] hold exp(-(0.5t-11.5)^2 * inv2s)
__device__ __forceinline__ float gtap(float t, float inv2s) {
    float ax = 0.5f * t - 11.5f;
    float g = expf(-ax * ax * inv2s);
    return (t >= 12.5f && t <= 33.5f) ? g : 0.0f;
}

// KY_T[y][p] (opacity folded), KX_T[x][p]
__global__ void build_kykx(const float* __restrict__ sx, const float* __restrict__ sy,
                           const float* __restrict__ op,
                           float* __restrict__ KY_T, float* __restrict__ KX_T) {
    int flat = blockIdx.x * 256 + threadIdx.x;      // 48*2304 = 110592
    if (flat >= 48 * NPTS) return;
    int pos = flat / NPTS;
    int p   = flat - pos * NPTS;
    int i = p / 48;
    int j = p - i * 48;
    float sxv = sx[p], syv = sy[p], opv = op[p];
    float invx = 0.5f / (sxv * sxv);  // h-axis uses sigma_x (reference: xx2/sx2 on axis 1)
    float invy = 0.5f / (syv * syv);

    float py = (float)pos + 23.5f - (47.0f / 48.0f) * (float)i;
    float y0 = floorf(py), fy = py - y0;
    KY_T[flat] = opv * (gtap(y0, invx) * (1.0f - fy) + gtap(y0 + 1.0f, invx) * fy);

    float px = (float)pos + 23.5f - (47.0f / 48.0f) * (float)j;
    float x0 = floorf(px), fx = px - x0;
    KX_T[flat] = gtap(x0, invy) * (1.0f - fx) + gtap(x0 + 1.0f, invy) * fx;
}

// Kt[hw][p] = (f16)(KY_T[y][p]*KX_T[x][p]) ; 8 points/thread, vectorized
__global__ void build_kt(const float* __restrict__ KY_T, const float* __restrict__ KX_T,
                         f16* __restrict__ Kt) {
    int idx = blockIdx.x * 256 + threadIdx.x;       // 2304*288 = 663552 chunks
    int hw = idx / 288;
    int p0 = (idx - hw * 288) * 8;
    int y = hw / 48, x = hw - y * 48;
    const float4* ky = (const float4*)(KY_T + (size_t)y * NPTS + p0);
    const float4* kx = (const float4*)(KX_T + (size_t)x * NPTS + p0);
    float4 a0 = ky[0], a1 = ky[1];
    float4 b0 = kx[0], b1 = kx[1];
    f16x8 r;
    r[0] = (f16)(a0.x * b0.x); r[1] = (f16)(a0.y * b0.y);
    r[2] = (f16)(a0.z * b0.z); r[3] = (f16)(a0.w * b0.w);
    r[4] = (f16)(a1.x * b1.x); r[5] = (f16)(a1.y * b1.y);
    r[6] = (f16)(a1.z * b1.z); r[7] = (f16)(a1.w * b1.w);
    *(f16x8*)(Kt + (size_t)hw * NPTS + p0) = r;
}

// A[m][p] fp16, m = bl*64 + c, p = i*48 + j ; 8 points/thread (never crosses a patch row)
__global__ void pack_A(const float* __restrict__ inp, f16* __restrict__ A) {
    int idx = blockIdx.x * 256 + threadIdx.x;       // 4096*288 = 1179648 chunks
    int m = idx / 288;
    int p0 = (idx - m * 288) * 8;
    int i = p0 / 48, j = p0 - i * 48;               // j in {0,8,...,40}, j+7 <= 47
    int bl = m >> 6, c = m & 63;
    int b = bl >> 4, pr = (bl >> 2) & 3, pc = bl & 3;
    const float* src = inp + ((size_t)(b * 64 + c) * HH + pr * 48 + i) * HH + pc * 48 + j;
    float4 a0 = *(const float4*)src;
    float4 a1 = *(const float4*)(src + 4);
    f16x8 r;
    r[0] = (f16)a0.x; r[1] = (f16)a0.y; r[2] = (f16)a0.z; r[3] = (f16)a0.w;
    r[4] = (f16)a1.x; r[5] = (f16)a1.y; r[6] = (f16)a1.z; r[7] = (f16)a1.w;
    *(f16x8*)(A + (size_t)m * KD + p0) = r;
}

// C[m][n] = sum_k A[m][k] * Bt[n][k], k restricted to the i-band of this n-tile.
__global__ __launch_bounds__(256) void gemm_splat(const f16* __restrict__ A,
                                                  const f16* __restrict__ Bt,
                                                  float* __restrict__ out) {
    __shared__ __attribute__((aligned(16))) f16 As[128 * 32];   // linear: gload_lds dest
    __shared__ __attribute__((aligned(16))) f16 Bs[128 * 32];

    int tid  = threadIdx.x;
    int lane = tid & 63;
    int w    = tid >> 6;
    int wr   = w >> 1, wc = w & 1;
    int bx   = blockIdx.x;
    int m0   = (bx / 18) * 128;
    int n0   = (bx % 18) * 128;

    // i-band for this n-tile (margin +-1 i; extra i's are exact zeros in Kt)
    int y_min = n0 / 48;
    int y_max = (n0 + 127) / 48;
    int i_lo = max(0,  (int)floorf((y_min - 10.5f) * (48.0f / 47.0f)));
    int i_hi = min(47, (int)ceilf ((y_max + 11.5f) * (48.0f / 47.0f)));
    int k_lo = (i_lo * 48) & ~31;
    int k_hi = min(KD, ((i_hi + 1) * 48 + 31) & ~31);

    // staging geometry: region r (0..7) = rows r*16..r*16+15 (1 KiB); wave w does r = w, w+4
    int srow = lane >> 2;             // row within region
    int sko  = (lane & 3) * 8;        // halves within row

    const int lrow = lane & 15;
    const int lk8  = (lane >> 4) * 8;

    f32x4 acc[4][4] = {};

    for (int k0 = k_lo; k0 < k_hi; k0 += 32) {
        #pragma unroll
        for (int c = 0; c < 2; ++c) {
            int r   = w + c * 4;
            int row = r * 16 + srow;
            gload16(&A [(size_t)(m0 + row) * KD + k0 + sko], &As[r * 512]);
            gload16(&Bt[(size_t)(n0 + row) * KD + k0 + sko], &Bs[r * 512]);
        }
        __syncthreads();

        f16x8 af[4], bf[4];
        #pragma unroll
        for (int mi = 0; mi < 4; ++mi)
            af[mi] = *(const f16x8*)&As[(wr * 64 + mi * 16 + lrow) * 32 + lk8];
        #pragma unroll
        for (int ni = 0; ni < 4; ++ni)
            bf[ni] = *(const f16x8*)&Bs[(wc * 64 + ni * 16 + lrow) * 32 + lk8];

        #pragma unroll
        for (int mi = 0; mi < 4; ++mi)
            #pragma unroll
            for (int ni = 0; ni < 4; ++ni)
                acc[mi][ni] = __builtin_amdgcn_mfma_f32_16x16x32_f16(af[mi], bf[ni], acc[mi][ni], 0, 0, 0);
        __syncthreads();
    }

    // epilogue: D row = (lane>>4)*4 + r, col = lane&15 (m89-verified C/D layout); clip + fold
    #pragma unroll
    for (int mi = 0; mi < 4; ++mi) {
        #pragma unroll
        for (int r = 0; r < 4; ++r) {
            int m  = m0 + wr * 64 + mi * 16 + (lane >> 4) * 4 + r;
            int bl = m >> 6, c = m & 63;
            int b  = bl >> 4, pr = (bl >> 2) & 3, pc = bl & 3;
            float* orow = out + ((size_t)(b * 64 + c) * HH + pr * 48) * HH + pc * 48;
            #pragma unroll
            for (int ni = 0; ni < 4; ++ni) {
                int n = n0 + wc * 64 + ni * 16 + (lane & 15);
                int y = n / 48, x = n - y * 48;
                float v = acc[mi][ni][r];
                v = fminf(fmaxf(v, 0.0f), 1.0f);
                orow[y * HH + x] = v;
            }
        }
    }
}

extern "C" void kernel_launch(void* const* d_in, const int* in_sizes, int n_in,
                              void* d_out, int out_size, void* d_ws, size_t ws_size,
                              hipStream_t stream) {
    const float* inp = (const float*)d_in[0];
    const float* sx  = (const float*)d_in[1];
    const float* sy  = (const float*)d_in[2];
    const float* op  = (const float*)d_in[3];
    float* out = (float*)d_out;

    char* ws = (char*)d_ws;
    float* KY_T = (float*)ws;                               //   442368 B
    float* KX_T = (float*)(ws + 442368);                    //   442368 B
    f16*   Kt   = (f16*)(ws + 884736);                      // 10616832 B  [2304][2304]
    f16*   Ap   = (f16*)(ws + 884736 + 10616832);           // 18874368 B  [4096][2304]

    build_kykx<<<dim3(432),  dim3(256), 0, stream>>>(sx, sy, op, KY_T, KX_T);
    build_kt  <<<dim3(2592), dim3(256), 0, stream>>>(KY_T, KX_T, Kt);
    pack_A    <<<dim3(4608), dim3(256), 0, stream>>>(inp, Ap);
    gemm_splat<<<dim3(576),  dim3(256), 0, stream>>>(Ap, Kt, out);
}